// Round 7
// baseline (88.014 us; speedup 1.0000x reference)
//
#include <hip/hip_runtime.h>
#include <stdint.h>

#define GLOBAL_AS __attribute__((address_space(1)))
#define LDS_AS    __attribute__((address_space(3)))

typedef __attribute__((ext_vector_type(8))) __bf16 bf16x8;
typedef __attribute__((ext_vector_type(4))) float  f32x4;

static_assert(sizeof(bf16x8) == 16, "bf16x8 must be 16B");

constexpr int N  = 4096;     // B*P rows
constexpr int DK = 512;      // feature dim
constexpr int NTILE = 272;   // sum_{rt=0..15} (2rt+2): 256x128 tiles over lower triangle
constexpr int PW = 48;       // partials width: 32 direct (gc) + 16 mirror (rt)

// ---------------------------------------------------------------------------
// ws layout:
//   Xb       : bf16 [4096][512]   @ 0          (4 MiB)  [dead after k_main]
//   cls      : int32[4096]        @ 4Mi        (16 KiB)
//   partials : float4 [4096][48]  @ 4Mi+16Ki   (3 MiB)  {S,P,E,W}
//   blockSums: float[1024]        @ 0          (aliases dead Xb; same-stream safe)
// ---------------------------------------------------------------------------

// blocks 0..1023: fp32->bf16 convert. block 1024: build cls.
__global__ void k_convert(const float* __restrict__ X, __bf16* __restrict__ Xb,
                          const int* __restrict__ tbuf, int* __restrict__ cls) {
    if (blockIdx.x == 1024) {
        __shared__ int is64;
        const int t = threadIdx.x;          // 256 threads
        if (t == 0) is64 = 1;
        __syncthreads();
        // int64 targets => odd int32 words zero; inspect first 1024 words (OOB-safe)
        if (tbuf[4 * t + 1] != 0 || tbuf[4 * t + 3] != 0) is64 = 0;
        __syncthreads();
        const int f = is64;
#pragma unroll
        for (int q = 0; q < 4; ++q) {
            const int ti = 4 * t + q;
            const int v = tbuf[f ? 2 * ti : ti];
            cls[4 * ti + 0] = v; cls[4 * ti + 1] = v;
            cls[4 * ti + 2] = v; cls[4 * ti + 3] = v;
        }
        return;
    }
    int idx = blockIdx.x * blockDim.x + threadIdx.x;
    const float4* s = (const float4*)X;
    float4 a = s[2 * idx + 0];
    float4 b = s[2 * idx + 1];
    bf16x8 o;
    o[0] = (__bf16)a.x; o[1] = (__bf16)a.y; o[2] = (__bf16)a.z; o[3] = (__bf16)a.w;
    o[4] = (__bf16)b.x; o[5] = (__bf16)b.y; o[6] = (__bf16)b.z; o[7] = (__bf16)b.w;
    *(bf16x8*)(Xb + 8 * idx) = o;
}

// Triangular 256x128-tile fused GEMM+stats. 512 thr = 8 waves (4x2), each wave
// 64x64 output (acc[4][4]); BK=32, 16 K-iters; 3-buf pipeline with counted
// vmcnt (R6-verified ordering). Grid 272 = all tiles co-resident (2 blocks/CU).
// Tile (rt,gc): rows [rt*256,+256), cols [gc*128,+128), gc < 2rt+2.
// fullyBelow (gc<2rt) also folds mirror col-stats (symmetric prod).
__launch_bounds__(512, 4)
__global__ void k_main(const __bf16* __restrict__ Xb, const int* __restrict__ cls,
                       float* __restrict__ partials) {
    __shared__ __align__(16) char smem[3][24576];   // 3 bufs: 384 rows x 64B (A:256,B:128)
    __shared__ int rowcls[256], colcls[128];
    float4* accR = (float4*)&smem[0][0];   // [2][256] row stats (epilogue alias)
    float4* accC = (float4*)&smem[1][0];   // [4][128] col stats (epilogue alias)

    const int tid  = threadIdx.x;
    const int lane = tid & 63;
    const int wid  = tid >> 6;          // 0..7
    const int wr   = wid >> 1;          // 0..3 : rows wr*64..+63
    const int wc   = wid & 1;           // 0..1 : cols wc*64..+63
    const int rA   = lane & 15;
    const int kgrp = lane >> 4;
    const char* xb = (const char*)Xb;

    // XCD-aware bijective map over tiles (272 = 8*34): same-rt tiles share L2
    const int bid = (blockIdx.x & 7) * 34 + (blockIdx.x >> 3);
    // decode: id = rt*(rt+1) + gc, gc in [0, 2rt+2)
    int rt = (int)((sqrtf(4.0f * (float)bid + 1.0f) - 1.0f) * 0.5f);
    while ((rt + 1) * (rt + 2) <= bid) ++rt;
    while (rt * (rt + 1) > bid) --rt;
    const int gc = bid - rt * (rt + 1);
    const int i0 = rt * 256;
    const int j0 = gc * 128;
    const bool fullyBelow = (gc < 2 * rt);

    if (tid < 256) rowcls[tid] = cls[i0 + tid];
    else if (tid < 384) colcls[tid - 256] = cls[j0 + (tid - 256)];

    // per-thread invariant staging source offsets (3 x 16B per K-step)
    size_t gbase[3];
#pragma unroll
    for (int q = 0; q < 3; ++q) {
        const int l    = q * 512 + tid;
        const int prow = l >> 2;                      // 0..383
        const int csrc = (l & 3) ^ ((prow >> 1) & 3); // pre-swizzled chunk (rule #21)
        const int grow = (prow < 256) ? (i0 + prow) : (j0 + prow - 256);
        gbase[q] = (size_t)grow * 1024 + (size_t)(csrc * 16);
    }

#define STAGE(bslot, kt)                                                       \
    {                                                                          \
        char* dst = &smem[(bslot)][0];                                         \
        const size_t kb = (size_t)(kt) * 64;                                   \
        _Pragma("unroll")                                                      \
        for (int q = 0; q < 3; ++q) {                                          \
            __builtin_amdgcn_global_load_lds(                                  \
                (const GLOBAL_AS void*)(xb + gbase[q] + kb),                   \
                (LDS_AS void*)(dst + q * 8192 + wid * 1024), 16, 0, 0);        \
        }                                                                      \
    }

    STAGE(0, 0);
    STAGE(1, 1);

    f32x4 acc[4][4] = {};

#pragma unroll
    for (int t = 0; t < 16; ++t) {
        // drain own stage-t loads (stage t+1 stays in flight); barrier => all
        // waves' stage-t landed. (cls loads are older; drained harmlessly at t=0)
        if (t < 15) { asm volatile("s_waitcnt vmcnt(3)" ::: "memory"); }
        else        { asm volatile("s_waitcnt vmcnt(0)" ::: "memory"); }
        __builtin_amdgcn_s_barrier();
        asm volatile("" ::: "memory");
        if (t + 2 < 16) STAGE((t + 2) % 3, t + 2);   // post-barrier: no overwrite race
        const char* bp = &smem[t % 3][0];
        bf16x8 af[4], bg[4];
#pragma unroll
        for (int m = 0; m < 4; ++m) {
            const int pr = wr * 64 + m * 16 + rA;
            af[m] = *(const bf16x8*)(bp + pr * 64 + ((kgrp ^ ((pr >> 1) & 3)) << 4));
        }
#pragma unroll
        for (int n = 0; n < 4; ++n) {
            const int pr = 256 + wc * 64 + n * 16 + rA;
            bg[n] = *(const bf16x8*)(bp + pr * 64 + ((kgrp ^ ((pr >> 1) & 3)) << 4));
        }
        // swapped operands: D[j][i] => i on rA axis, j on kgrp*4+reg axis
#pragma unroll
        for (int m = 0; m < 4; ++m)
#pragma unroll
            for (int n = 0; n < 4; ++n)
                acc[m][n] = __builtin_amdgcn_mfma_f32_16x16x32_bf16(bg[n], af[m],
                                                                    acc[m][n], 0, 0, 0);
    }
#undef STAGE

    __syncthreads();   // all reads of smem bufs done -> stats aliases safe

    // epilogue: p(i,j), i = wr*64+m*16+rA, j = wc*64+n*16+kgrp*4+r
    // part(i) = rA&3, part(j) = r   (all tile bases %4 == 0)
    const int pi = rA & 3;
    int ci[4];
#pragma unroll
    for (int m = 0; m < 4; ++m) ci[m] = rowcls[wr * 64 + m * 16 + rA];
    float rS[4] = {0.f, 0.f, 0.f, 0.f};
    float rP[4] = {0.f, 0.f, 0.f, 0.f};
    float rE[4] = {0.f, 0.f, 0.f, 0.f};
    float rW[4] = {0.f, 0.f, 0.f, 0.f};

#pragma unroll
    for (int n = 0; n < 4; ++n) {
#pragma unroll
        for (int r = 0; r < 4; ++r) {
            const int cj = colcls[wc * 64 + n * 16 + kgrp * 4 + r];
            float cS = 0.f, cP = 0.f, cE = 0.f, cW = 0.f;
#pragma unroll
            for (int m = 0; m < 4; ++m) {
                const float p  = acc[m][n][r];
                const float ep = __expf(p);
                const bool sc = (ci[m] == cj);
                const bool sp = (pi == r);
                if (!sc && !sp) { rS[m] += ep; cS += ep; }   // dadc
                const float w = (!sc && sp) ? 2.f : ((sc && !sp) ? 1.f : 0.f);
                rP[m] += w * p;  rE[m] += w * ep;  rW[m] += w;
                cP += w * p;     cE += w * ep;     cW += w;
            }
            if (fullyBelow) {   // reduce over i (rA axis)
#pragma unroll
                for (int off = 1; off < 16; off <<= 1) {
                    cS += __shfl_xor(cS, off);
                    cP += __shfl_xor(cP, off);
                    cE += __shfl_xor(cE, off);
                    cW += __shfl_xor(cW, off);
                }
                if (rA == 0)
                    accC[wr * 128 + wc * 64 + n * 16 + kgrp * 4 + r] =
                        make_float4(cS, cP, cE, cW);
            }
        }
    }
    // row stats: reduce over j (kgrp axis): 2 shfl steps
#pragma unroll
    for (int m = 0; m < 4; ++m) {
        float vS = rS[m], vP = rP[m], vE = rE[m], vW = rW[m];
        vS += __shfl_xor(vS, 16); vS += __shfl_xor(vS, 32);
        vP += __shfl_xor(vP, 16); vP += __shfl_xor(vP, 32);
        vE += __shfl_xor(vE, 16); vE += __shfl_xor(vE, 32);
        vW += __shfl_xor(vW, 16); vW += __shfl_xor(vW, 32);
        if (kgrp == 0) accR[wc * 256 + wr * 64 + m * 16 + rA] = make_float4(vS, vP, vE, vW);
    }

    __syncthreads();
    if (tid < 256) {   // fixed-order sums => deterministic
        float4 a0 = accR[tid], a1 = accR[256 + tid];
        ((float4*)partials)[(size_t)(i0 + tid) * PW + gc] =
            make_float4(a0.x + a1.x, a0.y + a1.y, a0.z + a1.z, a0.w + a1.w);
    } else if (tid < 384 && fullyBelow) {
        const int c = tid - 256;
        float4 c0 = accC[c], c1 = accC[128 + c], c2 = accC[256 + c], c3 = accC[384 + c];
        ((float4*)partials)[(size_t)(j0 + c) * PW + 32 + rt] =
            make_float4(c0.x + c1.x + c2.x + c3.x, c0.y + c1.y + c2.y + c3.y,
                        c0.z + c1.z + c2.z + c3.z, c0.w + c1.w + c2.w + c3.w);
    }
}

// 1 row per wave; sum only the slots k_main actually wrote for this row:
// direct gc in [0, 2*(row>>8)+2); mirror rt in [((row>>7)+2)>>1, 16).
__global__ void k_rowloss(const float* __restrict__ partials, float* __restrict__ blockSums) {
    __shared__ float red[4];
    const int tid = threadIdx.x;
    const int lane = tid & 63;
    const int w = tid >> 6;
    const int row = blockIdx.x * 4 + w;
    const int dEnd   = 2 * (row >> 8) + 2;
    const int mStart = ((row >> 7) + 2) >> 1;

    const float4* p = (const float4*)partials + (size_t)row * PW;
    float S = 0.f, P = 0.f, E = 0.f, W_ = 0.f;
    if (lane < PW) {
        const bool valid = (lane < 32) ? (lane < dEnd) : ((lane - 32) >= mStart);
        if (valid) {
            float4 v = p[lane];
            S = v.x; P = v.y; E = v.z; W_ = v.w;
        }
    }
#pragma unroll
    for (int off = 1; off < 64; off <<= 1) {
        S += __shfl_xor(S, off);
        P += __shfl_xor(P, off);
        E += __shfl_xor(E, off);
        W_ += __shfl_xor(W_, off);
    }
    if (lane == 0) red[w] = W_ * logf(S) - P + E / S;
    __syncthreads();
    if (tid == 0) blockSums[blockIdx.x] = red[0] + red[1] + red[2] + red[3];
}

__global__ void k_final2(const float* __restrict__ blockSums, float* __restrict__ out) {
    __shared__ float red[4];
    const int t = threadIdx.x;   // 256
    float v = blockSums[t] + blockSums[t + 256] + blockSums[t + 512] + blockSums[t + 768];
#pragma unroll
    for (int off = 1; off < 64; off <<= 1) v += __shfl_xor(v, off);
    if ((t & 63) == 0) red[t >> 6] = v;
    __syncthreads();
    if (t == 0) out[0] = (red[0] + red[1] + red[2] + red[3]) / (float)N;
}

extern "C" void kernel_launch(void* const* d_in, const int* in_sizes, int n_in,
                              void* d_out, int out_size, void* d_ws, size_t ws_size,
                              hipStream_t stream) {
    const float* X = (const float*)d_in[0];
    const int*   T = (const int*)d_in[1];
    float* out = (float*)d_out;

    char* ws = (char*)d_ws;
    __bf16* Xb    = (__bf16*)ws;
    int*    cls   = (int*)(ws + (size_t)4 * 1024 * 1024);
    float*  parts = (float*)(ws + (size_t)4 * 1024 * 1024 + 16 * 1024);
    float*  bsums = (float*)ws;   // aliases Xb (dead after k_main; same-stream ordering)

    hipLaunchKernelGGL(k_convert, dim3(1025),  dim3(256), 0, stream, X, Xb, T, cls);
    hipLaunchKernelGGL(k_main,    dim3(NTILE), dim3(512), 0, stream, Xb, cls, parts);
    hipLaunchKernelGGL(k_rowloss, dim3(1024),  dim3(256), 0, stream, parts, bsums);
    hipLaunchKernelGGL(k_final2,  dim3(1),     dim3(256), 0, stream, bsums, out);
}